// Round 2
// baseline (1121.307 us; speedup 1.0000x reference)
//
#include <hip/hip_runtime.h>
#include <hip/hip_bf16.h>
#include <math.h>

// ---------------------------------------------------------------------------
// VQ quantizer:
//   in[0] = z        (16,256,32,32) fp32   -> N=16384 vectors of C=256 (needs transpose)
//   in[1] = codebook (8192,256)     fp32
//   out   = [ z_q (B,C,H,W) 4194304 | loss | ortho | perplexity | idx(16384) as float ]
//
// idx semantics: the reference computes d = (||z||^2 + ||e||^2) - 2 z.e in fp32.
// ||z||^2 ~ 256 so d rounds on a grid of ulp(256)=3e-5 while the j-varying term
// has std 7e-5 -> hundreds of exact fp32 ties at the min; argmin = lowest index.
// We replicate the exact fp32 rounding: d = RN(RN(A_n + ce_j) - 2*dot). A_n only
// needs to be *some* fp32 row norm (grid shifts by whole ulps preserve ties).
// ---------------------------------------------------------------------------

#define N_E     8192
#define C_DIM   256
#define N_VEC   16384            // 16*32*32
#define N_ELEM  4194304          // 16*256*32*32

// ws layout (bytes)
#define WS_COUNTS   0            // int[8192]                32768
#define WS_M        32768        // float[65536]             262144
#define WS_ACCUM    294912       // double[2] {sse, -}       16
#define WS_KEYS     294928       // u64[16384]               131072
#define WS_CE       426000       // float[8192]              32768
#define WS_RN       458768       // float[8192]              32768
#define WS_IDXI     491536       // int[16384]               65536
#define WS_A        557072       // float[16384]             65536
#define WS_ZERO_BYTES 294928
#define WS_KEYS_BYTES 131072

// ---------------------------------------------------------------------------
// codebook row squared norms + reciprocal norms
__global__ __launch_bounds__(256) void k_sqnorm(const float* __restrict__ cb,
                                                float* __restrict__ ce,
                                                float* __restrict__ rn) {
    int j = blockIdx.x;
    int tid = threadIdx.x;
    float v = cb[(size_t)j * C_DIM + tid];
    float s = v * v;
    #pragma unroll
    for (int off = 32; off > 0; off >>= 1) s += __shfl_down(s, off, 64);
    __shared__ float sh[4];
    if ((tid & 63) == 0) sh[tid >> 6] = s;
    __syncthreads();
    if (tid == 0) {
        float t = sh[0] + sh[1] + sh[2] + sh[3];
        ce[j] = t;
        rn[j] = 1.0f / sqrtf(t);
    }
}

// ---------------------------------------------------------------------------
// z row squared norms: A[n] = fp32 sum_k z[n,k]^2 (deterministic sequential order;
// exact order is irrelevant to the argmin -- uniform ulp shifts preserve ties)
__global__ __launch_bounds__(256) void k_znorm(const float* __restrict__ z,
                                               float* __restrict__ A) {
    int n = blockIdx.x * 256 + threadIdx.x;      // n = b*1024 + hw
    int b = n >> 10, hw = n & 1023;
    const float* zp = z + (size_t)b * 262144 + hw;
    float a = 0.0f;
    #pragma unroll 8
    for (int c = 0; c < C_DIM; ++c) {
        float v = zp[(size_t)c * 1024];
        a = fmaf(v, v, a);
    }
    A[n] = a;
}

// ---------------------------------------------------------------------------
// main distance + argmin kernel.
// tile: 64 n-rows x 128 j-cols, K chunked by 64.  grid = (256 n-tiles, 4 j-slices)
#define TN 64
#define TJ 128
#define KC 64
#define NJIT 16   // 2048 / TJ

__global__ __launch_bounds__(256) void k_dist(const float* __restrict__ z,
                                              const float* __restrict__ cb,
                                              const float* __restrict__ ce,
                                              const float* __restrict__ A,
                                              unsigned long long* __restrict__ keys) {
    __shared__ float zT[TN][KC + 1];    // [n][k]  pad 65 -> conflict-free
    __shared__ float eT[KC][TJ + 4];    // [k][j]  pad 132 -> rows 16B-aligned for b128 reads

    const int tid = threadIdx.x;
    const int tj = tid & 15, tn = tid >> 4;
    const int n0 = blockIdx.x * TN;
    const int base_b = (n0 >> 10) * C_DIM;   // b*256
    const int hw0 = n0 & 1023;
    const int j0base = blockIdx.y * (N_E / 4);

    float Arow[4];
    #pragma unroll
    for (int i = 0; i < 4; ++i) Arow[i] = A[n0 + tn * 4 + i];

    float best[4];
    int bidx[4];
    #pragma unroll
    for (int i = 0; i < 4; ++i) { best[i] = 3.0e38f; bidx[i] = 0; }

    for (int jt = 0; jt < NJIT; ++jt) {
        const int j0 = j0base + jt * TJ;
        float acc[4][8];
        #pragma unroll
        for (int i = 0; i < 4; ++i)
            #pragma unroll
            for (int jj = 0; jj < 8; ++jj) acc[i][jj] = 0.0f;

        for (int kc = 0; kc < C_DIM; kc += KC) {
            __syncthreads();
            {   // stage z chunk (transpose (c, hw) -> [n][k]); lanes coalesced over hw
                const int hw = tid & 63, kk0 = tid >> 6;
                const float* zp = z + (size_t)(base_b + kc + kk0) * 1024 + hw0 + hw;
                #pragma unroll
                for (int p = 0; p < 16; ++p)
                    zT[hw][p * 4 + kk0] = zp[(size_t)p * 4096];
            }
            {   // stage codebook chunk -> [k][j]; lanes coalesced over k
                const int kk = tid & 63, jj0 = tid >> 6;
                const float* cp = cb + (size_t)(j0 + jj0) * C_DIM + kc + kk;
                #pragma unroll
                for (int p = 0; p < 32; ++p)
                    eT[kk][p * 4 + jj0] = cp[(size_t)p * 1024];
            }
            __syncthreads();

            #pragma unroll 4
            for (int k = 0; k < KC; ++k) {
                float ev[8];
                *(float4*)&ev[0] = *(const float4*)&eT[k][tj * 8];
                *(float4*)&ev[4] = *(const float4*)&eT[k][tj * 8 + 4];
                float zv[4];
                #pragma unroll
                for (int i = 0; i < 4; ++i) zv[i] = zT[tn * 4 + i][k];
                #pragma unroll
                for (int i = 0; i < 4; ++i)
                    #pragma unroll
                    for (int jj = 0; jj < 8; ++jj)
                        acc[i][jj] = fmaf(zv[i], ev[jj], acc[i][jj]);
            }
        }

        // fold this j-tile into the running argmin, replicating reference fp32 rounding:
        // d = RN( RN(A_n + ce_j) - 2*dot )   (x2 is exact, so fmaf = numpy's two steps)
        #pragma unroll
        for (int jj = 0; jj < 8; ++jj) {
            const int j = j0 + tj * 8 + jj;
            const float cej = ce[j];
            #pragma unroll
            for (int i = 0; i < 4; ++i) {
                float t = Arow[i] + cej;                  // rounds to Arow[i] (e2 < half-ulp)
                float d = fmaf(-2.0f, acc[i][jj], t);     // single rounding, == ref
                if (d < best[i]) { best[i] = d; bidx[i] = j; }
            }
        }
    }

    // one packed atomicMin per (thread, row): (sortable(score) << 32) | j
    // -> global min, lowest index among exact fp32 ties (matches np.argmin)
    #pragma unroll
    for (int i = 0; i < 4; ++i) {
        unsigned int fb = __float_as_uint(best[i]);
        fb = (fb & 0x80000000u) ? ~fb : (fb | 0x80000000u);
        unsigned long long key = ((unsigned long long)fb << 32) | (unsigned int)bidx[i];
        atomicMin(&keys[n0 + tn * 4 + i], key);
    }
}

// ---------------------------------------------------------------------------
// unpack keys -> idx (int + float out), histogram counts
__global__ __launch_bounds__(256) void k_combine(const unsigned long long* __restrict__ keys,
                                                 int* __restrict__ idxi,
                                                 float* __restrict__ out_idx,
                                                 int* __restrict__ counts) {
    int n = blockIdx.x * 256 + threadIdx.x;
    unsigned long long k = keys[n];
    int idx = (int)(k & 0xFFFFFFFFull);
    idxi[n] = idx;
    out_idx[n] = (float)idx;
    atomicAdd(&counts[idx], 1);
}

// ---------------------------------------------------------------------------
// gather z_q (write in (B,C,H,W) layout) + fp64 SSE reduction for the loss
__global__ __launch_bounds__(256) void k_gather(const float* __restrict__ z,
                                                const float* __restrict__ cb,
                                                const int* __restrict__ idxi,
                                                float* __restrict__ out,
                                                double* __restrict__ sse) {
    int bh = blockIdx.x;                 // b*32 + h
    int b = bh >> 5, h = bh & 31;
    int tid = threadIdx.x;
    int w = tid & 31, cy = tid >> 5;
    int n = b * 1024 + h * 32 + w;
    int jid = idxi[n];
    const float* cbr = cb + (size_t)jid * C_DIM;
    size_t zb = (size_t)b * 262144 + h * 32 + w;

    double acc = 0.0;
    #pragma unroll 4
    for (int cc = 0; cc < 32; ++cc) {
        int c = cc * 8 + cy;
        float e = cbr[c];
        size_t zi = zb + (size_t)c * 1024;
        float d = e - z[zi];
        out[zi] = e;
        acc += (double)(d * d);
    }
    #pragma unroll
    for (int off = 32; off > 0; off >>= 1) acc += __shfl_down(acc, off, 64);
    __shared__ double sh[4];
    if ((tid & 63) == 0) sh[tid >> 6] = acc;
    __syncthreads();
    if (tid == 0) atomicAdd(sse, sh[0] + sh[1] + sh[2] + sh[3]);
}

// ---------------------------------------------------------------------------
// Gram matrix M = Wn^T Wn  (256x256), j-split with float atomics
__global__ __launch_bounds__(256) void k_gram(const float* __restrict__ cb,
                                              const float* __restrict__ rn,
                                              float* __restrict__ M) {
    __shared__ float aT[64][68];
    __shared__ float bT[64][68];
    int k0 = blockIdx.x * 64, l0 = blockIdx.y * 64;
    int jc0 = blockIdx.z * 256;
    int tid = threadIdx.x;
    int tk = tid & 15, tl = tid >> 4;
    float acc[4][4];
    #pragma unroll
    for (int i = 0; i < 4; ++i)
        #pragma unroll
        for (int l = 0; l < 4; ++l) acc[i][l] = 0.0f;

    for (int jc = jc0; jc < jc0 + 256; jc += 64) {
        __syncthreads();
        {
            int kk = tid & 63, jj0 = tid >> 6;
            #pragma unroll
            for (int p = 0; p < 16; ++p) {
                int jj = p * 4 + jj0;
                float r = rn[jc + jj];
                const float* row = cb + (size_t)(jc + jj) * C_DIM;
                aT[jj][kk] = row[k0 + kk] * r;
                bT[jj][kk] = row[l0 + kk] * r;
            }
        }
        __syncthreads();
        #pragma unroll 8
        for (int jj = 0; jj < 64; ++jj) {
            float4 av = *(const float4*)&aT[jj][tk * 4];
            float4 bv = *(const float4*)&bT[jj][tl * 4];
            float a4[4] = {av.x, av.y, av.z, av.w};
            float b4[4] = {bv.x, bv.y, bv.z, bv.w};
            #pragma unroll
            for (int i = 0; i < 4; ++i)
                #pragma unroll
                for (int l = 0; l < 4; ++l)
                    acc[i][l] = fmaf(a4[i], b4[l], acc[i][l]);
        }
    }
    #pragma unroll
    for (int i = 0; i < 4; ++i)
        #pragma unroll
        for (int l = 0; l < 4; ++l)
            atomicAdd(&M[(size_t)(k0 + tk * 4 + i) * C_DIM + l0 + tl * 4 + l], acc[i][l]);
}

// ---------------------------------------------------------------------------
// finalize scalars: loss, ortho = (||M||_F^2 - n_e)/n_e^2, perplexity
__global__ __launch_bounds__(256) void k_final(const float* __restrict__ M,
                                               const int* __restrict__ counts,
                                               const double* __restrict__ accum,
                                               float* __restrict__ out_scalars) {
    int tid = threadIdx.x;
    __shared__ double sh[4];

    double s = 0.0;
    for (int i = tid; i < C_DIM * C_DIM; i += 256) {
        double m = M[i];
        s += m * m;
    }
    #pragma unroll
    for (int off = 32; off > 0; off >>= 1) s += __shfl_down(s, off, 64);
    if ((tid & 63) == 0) sh[tid >> 6] = s;
    __syncthreads();
    double S = sh[0] + sh[1] + sh[2] + sh[3];
    __syncthreads();

    double H = 0.0;
    for (int j = tid; j < N_E; j += 256) {
        double p = counts[j] * (1.0 / (double)N_VEC);
        H += p * log(p + 1e-10);
    }
    #pragma unroll
    for (int off = 32; off > 0; off >>= 1) H += __shfl_down(H, off, 64);
    if ((tid & 63) == 0) sh[tid >> 6] = H;
    __syncthreads();

    if (tid == 0) {
        double Hs = sh[0] + sh[1] + sh[2] + sh[3];
        out_scalars[0] = (float)(1.25 * accum[0] / (double)N_ELEM);        // loss
        out_scalars[1] = (float)((S - (double)N_E) / ((double)N_E * N_E)); // ortho
        out_scalars[2] = (float)exp(-Hs);                                  // perplexity
    }
}

// ---------------------------------------------------------------------------
extern "C" void kernel_launch(void* const* d_in, const int* in_sizes, int n_in,
                              void* d_out, int out_size, void* d_ws, size_t ws_size,
                              hipStream_t stream) {
    (void)in_sizes; (void)n_in; (void)out_size; (void)ws_size;
    const float* z  = (const float*)d_in[0];
    const float* cb = (const float*)d_in[1];
    float* out = (float*)d_out;

    char* ws = (char*)d_ws;
    int* counts               = (int*)(ws + WS_COUNTS);
    float* M                  = (float*)(ws + WS_M);
    double* accum             = (double*)(ws + WS_ACCUM);
    unsigned long long* keys  = (unsigned long long*)(ws + WS_KEYS);
    float* ce                 = (float*)(ws + WS_CE);
    float* rn                 = (float*)(ws + WS_RN);
    int* idxi                 = (int*)(ws + WS_IDXI);
    float* A                  = (float*)(ws + WS_A);

    float* out_scalars = out + N_ELEM;       // loss, ortho, perplexity
    float* out_idx     = out + N_ELEM + 3;   // 16384 idx as float

    hipMemsetAsync(ws, 0, WS_ZERO_BYTES, stream);
    hipMemsetAsync(ws + WS_KEYS, 0xFF, WS_KEYS_BYTES, stream);

    k_sqnorm<<<N_E, 256, 0, stream>>>(cb, ce, rn);
    k_znorm<<<N_VEC / 256, 256, 0, stream>>>(z, A);
    k_dist<<<dim3(N_VEC / TN, 4), 256, 0, stream>>>(z, cb, ce, A, keys);
    k_combine<<<N_VEC / 256, 256, 0, stream>>>(keys, idxi, out_idx, counts);
    k_gather<<<512, 256, 0, stream>>>(z, cb, idxi, out, accum);
    k_gram<<<dim3(4, 4, 32), 256, 0, stream>>>(cb, rn, M);
    k_final<<<1, 256, 0, stream>>>(M, counts, accum, out_scalars);
}

// Round 3
// 958.095 us; speedup vs baseline: 1.1704x; 1.1704x over previous
//
#include <hip/hip_runtime.h>
#include <hip/hip_bf16.h>
#include <math.h>

// ---------------------------------------------------------------------------
// VQ quantizer:
//   in[0] = z        (16,256,32,32) fp32   -> N=16384 vectors of C=256
//   in[1] = codebook (8192,256)     fp32
//   out   = [ z_q (B,C,H,W) 4194304 | loss | ortho | perplexity | idx(16384) as float ]
//
// idx semantics: reference d = RN(RN(A_n + ce_j) - 2*dot) collapses onto the
// ulp(A_n) grid; we replicate that rounding exactly. INVARIANT (do not break):
// per (n,j) the dot is ONE fp32 fmaf chain, k ascending 0..255, init 0.0f,
// epilogue t = A[n]+ce[j]; d = fmaf(-2,acc,t). This makes d bit-identical
// across kernel restructurings -> idx provably unchanged vs the passing R2 run.
// ---------------------------------------------------------------------------

#define N_E     8192
#define C_DIM   256
#define N_VEC   16384            // 16*32*32
#define N_ELEM  4194304          // 16*256*32*32

// ws layout (bytes)
#define WS_COUNTS   0            // int[8192]                32768
#define WS_M        32768        // float[65536]             262144
#define WS_ACCUM    294912       // double[2] {sse, -}       16
#define WS_KEYS     294928       // u64[16384]               131072
#define WS_CE       426000       // float[8192]              32768
#define WS_RN       458768       // float[8192]              32768
#define WS_IDXI     491536       // int[16384]               65536
#define WS_A        557072       // float[16384]             65536
#define WS_ZERO_BYTES 294928
#define WS_KEYS_BYTES 131072

// ---------------------------------------------------------------------------
// codebook row squared norms + reciprocal norms
__global__ __launch_bounds__(256) void k_sqnorm(const float* __restrict__ cb,
                                                float* __restrict__ ce,
                                                float* __restrict__ rn) {
    int j = blockIdx.x;
    int tid = threadIdx.x;
    float v = cb[(size_t)j * C_DIM + tid];
    float s = v * v;
    #pragma unroll
    for (int off = 32; off > 0; off >>= 1) s += __shfl_down(s, off, 64);
    __shared__ float sh[4];
    if ((tid & 63) == 0) sh[tid >> 6] = s;
    __syncthreads();
    if (tid == 0) {
        float t = sh[0] + sh[1] + sh[2] + sh[3];
        ce[j] = t;
        rn[j] = 1.0f / sqrtf(t);
    }
}

// ---------------------------------------------------------------------------
// z row squared norms (unchanged from R2 -> A bits identical)
__global__ __launch_bounds__(256) void k_znorm(const float* __restrict__ z,
                                               float* __restrict__ A) {
    int n = blockIdx.x * 256 + threadIdx.x;      // n = b*1024 + hw
    int b = n >> 10, hw = n & 1023;
    const float* zp = z + (size_t)b * 262144 + hw;
    float a = 0.0f;
    #pragma unroll 8
    for (int c = 0; c < C_DIM; ++c) {
        float v = zp[(size_t)c * 1024];
        a = fmaf(v, v, a);
    }
    A[n] = a;
}

// ---------------------------------------------------------------------------
// distance + argmin, v2: 128n x 128j tile per block, 8x8 per thread.
//   zT [k][u]  stride 132 floats (528B rows, 16B aligned; 33 mod 8 = 1 -> b128
//              chunk groups diagonal-uniform for staging AND reads)
//   eT [j][k]  stride 36 floats (144B rows; 9 mod 8 = 1 -> same property; NO
//              transpose scatter: codebook staged row-major, read b128 along k)
// thread (tx,ty): n-frag = ty*8..+7 (contiguous, b128 z reads),
//                 j-frag = tx+16q, q=0..7 (row-spread, uniform 16B groups)
#define TN 128
#define TJ 128
#define KC 32
#define ZT_S 132
#define ET_S 36

__global__ __launch_bounds__(256, 4) void k_dist2(const float* __restrict__ z,
                                                  const float* __restrict__ cb,
                                                  const float* __restrict__ ce,
                                                  const float* __restrict__ A,
                                                  unsigned long long* __restrict__ keys) {
    __shared__ float zT[KC * ZT_S];
    __shared__ float eT[TJ * ET_S];

    const int tid = threadIdx.x;
    const int tx = tid & 15, ty = tid >> 4;
    const int n0 = blockIdx.x * TN;
    const int j0 = blockIdx.y * TJ;
    const int b  = n0 >> 10;          // n0 multiple of 128 -> single b per tile
    const int hw0 = n0 & 1023;

    // staging decomposition (per thread: 4 float4 each for e and z)
    const int sj = tid >> 3;          // e: j-row (0..31, +32p)
    const int sk = (tid & 7) * 4;     // e: k0 within chunk
    const int zk = tid >> 3;          // z: k-row (0..31)
    const int zu = (tid & 7) * 4;     // z: u0 (+32p)

    float acc[8][8];
    #pragma unroll
    for (int p = 0; p < 8; ++p)
        #pragma unroll
        for (int q = 0; q < 8; ++q) acc[p][q] = 0.0f;

    for (int kc = 0; kc < C_DIM; kc += KC) {
        __syncthreads();
        #pragma unroll
        for (int p = 0; p < 4; ++p) {     // stage e tile (128 x 32)
            int jj = sj + 32 * p;
            float4 v = *(const float4*)&cb[(size_t)(j0 + jj) * C_DIM + kc + sk];
            *(float4*)&eT[jj * ET_S + sk] = v;
        }
        #pragma unroll
        for (int p = 0; p < 4; ++p) {     // stage z tile (32 x 128), k-major (no transpose)
            int u = zu + 32 * p;
            float4 v = *(const float4*)&z[(size_t)(b * C_DIM + kc + zk) * 1024 + hw0 + u];
            *(float4*)&zT[zk * ZT_S + u] = v;
        }
        __syncthreads();

        #pragma unroll
        for (int k4 = 0; k4 < KC; k4 += 4) {
            float4 ef[8];
            #pragma unroll
            for (int q = 0; q < 8; ++q)
                ef[q] = *(const float4*)&eT[(tx + 16 * q) * ET_S + k4];
            #pragma unroll
            for (int kk = 0; kk < 4; ++kk) {
                float zf[8];
                *(float4*)&zf[0] = *(const float4*)&zT[(k4 + kk) * ZT_S + ty * 8];
                *(float4*)&zf[4] = *(const float4*)&zT[(k4 + kk) * ZT_S + ty * 8 + 4];
                #pragma unroll
                for (int p = 0; p < 8; ++p)
                    #pragma unroll
                    for (int q = 0; q < 8; ++q)
                        acc[p][q] = fmaf(zf[p], ((const float*)&ef[q])[kk], acc[p][q]);
            }
        }
    }

    // epilogue: d = RN(RN(A+ce) - 2*acc); per-row argmin over this block's 128 j,
    // then one packed atomicMin per row from the lane-group leader.
    #pragma unroll
    for (int p = 0; p < 8; ++p) {
        const int n = n0 + ty * 8 + p;
        const float An = A[n];
        float bd = 3.4e38f;
        int   bj = 0;
        #pragma unroll
        for (int q = 0; q < 8; ++q) {
            int j = j0 + tx + 16 * q;
            float t = An + ce[j];
            float d = fmaf(-2.0f, acc[p][q], t);
            if (d < bd) { bd = d; bj = j; }      // q ascending => j ascending: strict < keeps lowest
        }
        unsigned int sd = __float_as_uint(bd);
        sd = (sd & 0x80000000u) ? ~sd : (sd | 0x80000000u);
        unsigned long long key = ((unsigned long long)sd << 32) | (unsigned int)bj;
        #pragma unroll
        for (int off = 8; off > 0; off >>= 1) {   // reduce over the 16 tx lanes
            unsigned long long o = __shfl_xor(key, off, 64);
            key = (o < key) ? o : key;
        }
        if (tx == 0) atomicMin(&keys[n], key);
    }
}

// ---------------------------------------------------------------------------
// unpack keys -> idx (int + float out), histogram counts
__global__ __launch_bounds__(256) void k_combine(const unsigned long long* __restrict__ keys,
                                                 int* __restrict__ idxi,
                                                 float* __restrict__ out_idx,
                                                 int* __restrict__ counts) {
    int n = blockIdx.x * 256 + threadIdx.x;
    unsigned long long k = keys[n];
    int idx = (int)(k & 0xFFFFFFFFull);
    idxi[n] = idx;
    out_idx[n] = (float)idx;
    atomicAdd(&counts[idx], 1);
}

// ---------------------------------------------------------------------------
// gather z_q (write in (B,C,H,W) layout) + fp64 SSE reduction for the loss
__global__ __launch_bounds__(256) void k_gather(const float* __restrict__ z,
                                                const float* __restrict__ cb,
                                                const int* __restrict__ idxi,
                                                float* __restrict__ out,
                                                double* __restrict__ sse) {
    int bh = blockIdx.x;                 // b*32 + h
    int b = bh >> 5, h = bh & 31;
    int tid = threadIdx.x;
    int w = tid & 31, cy = tid >> 5;
    int n = b * 1024 + h * 32 + w;
    int jid = idxi[n];
    const float* cbr = cb + (size_t)jid * C_DIM;
    size_t zb = (size_t)b * 262144 + h * 32 + w;

    double acc = 0.0;
    #pragma unroll 4
    for (int cc = 0; cc < 32; ++cc) {
        int c = cc * 8 + cy;
        float e = cbr[c];
        size_t zi = zb + (size_t)c * 1024;
        float d = e - z[zi];
        out[zi] = e;
        acc += (double)(d * d);
    }
    #pragma unroll
    for (int off = 32; off > 0; off >>= 1) acc += __shfl_down(acc, off, 64);
    __shared__ double sh[4];
    if ((tid & 63) == 0) sh[tid >> 6] = acc;
    __syncthreads();
    if (tid == 0) atomicAdd(sse, sh[0] + sh[1] + sh[2] + sh[3]);
}

// ---------------------------------------------------------------------------
// Gram matrix M = Wn^T Wn  (256x256), j-split with float atomics
__global__ __launch_bounds__(256) void k_gram(const float* __restrict__ cb,
                                              const float* __restrict__ rn,
                                              float* __restrict__ M) {
    __shared__ float aT[64][68];
    __shared__ float bT[64][68];
    int k0 = blockIdx.x * 64, l0 = blockIdx.y * 64;
    int jc0 = blockIdx.z * 256;
    int tid = threadIdx.x;
    int tk = tid & 15, tl = tid >> 4;
    float acc[4][4];
    #pragma unroll
    for (int i = 0; i < 4; ++i)
        #pragma unroll
        for (int l = 0; l < 4; ++l) acc[i][l] = 0.0f;

    for (int jc = jc0; jc < jc0 + 256; jc += 64) {
        __syncthreads();
        {
            int kk = tid & 63, jj0 = tid >> 6;
            #pragma unroll
            for (int p = 0; p < 16; ++p) {
                int jj = p * 4 + jj0;
                float r = rn[jc + jj];
                const float* row = cb + (size_t)(jc + jj) * C_DIM;
                aT[jj][kk] = row[k0 + kk] * r;
                bT[jj][kk] = row[l0 + kk] * r;
            }
        }
        __syncthreads();
        #pragma unroll 8
        for (int jj = 0; jj < 64; ++jj) {
            float4 av = *(const float4*)&aT[jj][tk * 4];
            float4 bv = *(const float4*)&bT[jj][tl * 4];
            float a4[4] = {av.x, av.y, av.z, av.w};
            float b4[4] = {bv.x, bv.y, bv.z, bv.w};
            #pragma unroll
            for (int i = 0; i < 4; ++i)
                #pragma unroll
                for (int l = 0; l < 4; ++l)
                    acc[i][l] = fmaf(a4[i], b4[l], acc[i][l]);
        }
    }
    #pragma unroll
    for (int i = 0; i < 4; ++i)
        #pragma unroll
        for (int l = 0; l < 4; ++l)
            atomicAdd(&M[(size_t)(k0 + tk * 4 + i) * C_DIM + l0 + tl * 4 + l], acc[i][l]);
}

// ---------------------------------------------------------------------------
// finalize scalars: loss, ortho = (||M||_F^2 - n_e)/n_e^2, perplexity
__global__ __launch_bounds__(256) void k_final(const float* __restrict__ M,
                                               const int* __restrict__ counts,
                                               const double* __restrict__ accum,
                                               float* __restrict__ out_scalars) {
    int tid = threadIdx.x;
    __shared__ double sh[4];

    double s = 0.0;
    for (int i = tid; i < C_DIM * C_DIM; i += 256) {
        double m = M[i];
        s += m * m;
    }
    #pragma unroll
    for (int off = 32; off > 0; off >>= 1) s += __shfl_down(s, off, 64);
    if ((tid & 63) == 0) sh[tid >> 6] = s;
    __syncthreads();
    double S = sh[0] + sh[1] + sh[2] + sh[3];
    __syncthreads();

    double H = 0.0;
    for (int j = tid; j < N_E; j += 256) {
        double p = counts[j] * (1.0 / (double)N_VEC);
        H += p * log(p + 1e-10);
    }
    #pragma unroll
    for (int off = 32; off > 0; off >>= 1) H += __shfl_down(H, off, 64);
    if ((tid & 63) == 0) sh[tid >> 6] = H;
    __syncthreads();

    if (tid == 0) {
        double Hs = sh[0] + sh[1] + sh[2] + sh[3];
        out_scalars[0] = (float)(1.25 * accum[0] / (double)N_ELEM);        // loss
        out_scalars[1] = (float)((S - (double)N_E) / ((double)N_E * N_E)); // ortho
        out_scalars[2] = (float)exp(-Hs);                                  // perplexity
    }
}

// ---------------------------------------------------------------------------
extern "C" void kernel_launch(void* const* d_in, const int* in_sizes, int n_in,
                              void* d_out, int out_size, void* d_ws, size_t ws_size,
                              hipStream_t stream) {
    (void)in_sizes; (void)n_in; (void)out_size; (void)ws_size;
    const float* z  = (const float*)d_in[0];
    const float* cb = (const float*)d_in[1];
    float* out = (float*)d_out;

    char* ws = (char*)d_ws;
    int* counts               = (int*)(ws + WS_COUNTS);
    float* M                  = (float*)(ws + WS_M);
    double* accum             = (double*)(ws + WS_ACCUM);
    unsigned long long* keys  = (unsigned long long*)(ws + WS_KEYS);
    float* ce                 = (float*)(ws + WS_CE);
    float* rn                 = (float*)(ws + WS_RN);
    int* idxi                 = (int*)(ws + WS_IDXI);
    float* A                  = (float*)(ws + WS_A);

    float* out_scalars = out + N_ELEM;       // loss, ortho, perplexity
    float* out_idx     = out + N_ELEM + 3;   // 16384 idx as float

    hipMemsetAsync(ws, 0, WS_ZERO_BYTES, stream);
    hipMemsetAsync(ws + WS_KEYS, 0xFF, WS_KEYS_BYTES, stream);

    k_sqnorm<<<N_E, 256, 0, stream>>>(cb, ce, rn);
    k_znorm<<<N_VEC / 256, 256, 0, stream>>>(z, A);
    k_dist2<<<dim3(N_VEC / TN, N_E / TJ), 256, 0, stream>>>(z, cb, ce, A, keys);
    k_combine<<<N_VEC / 256, 256, 0, stream>>>(keys, idxi, out_idx, counts);
    k_gather<<<512, 256, 0, stream>>>(z, cb, idxi, out, accum);
    k_gram<<<dim3(4, 4, 32), 256, 0, stream>>>(cb, rn, M);
    k_final<<<1, 256, 0, stream>>>(M, counts, accum, out_scalars);
}